// Round 3
// baseline (240.984 us; speedup 1.0000x reference)
//
#include <hip/hip_runtime.h>

// RoPE: out[..., 2k]   = cos*x[...,2k] - sin*x[...,2k+1]
//       out[..., 2k+1] = sin*x[...,2k] + cos*x[...,2k+1]
// x: (4,16,4096,128) fp32, tables: (8192,64) fp32, token_positions: (4096,) i32.
// Memory-bound: 128 MiB in + 128 MiB out -> 268 MB min HBM traffic,
// roofline ~42.6 us at 6.3 TB/s achievable.
//
// vs round 0:
//  - 32 B chunk per thread: cos/sin gathers become one dwordx4 each
//    (VMEM ops per 32 B of x: 10 -> 7)
//  - 4x grid-stride unroll: 4 independent load chains in flight per thread
//  - nontemporal load/store on streamed x/out (keeps cos/sin tables in L2)
//  - NOTE: out_size is in ELEMENTS (floats), not bytes -> /8 for 32B chunks.

typedef float f4 __attribute__((ext_vector_type(4)));

constexpr int SEQ        = 4096;
constexpr int D_K        = 128;
constexpr int CH_PER_ROW = D_K / 8;   // 16 x 32B chunks per 128-float row
constexpr int BLOCK      = 256;
constexpr int UNROLL     = 4;

__global__ __launch_bounds__(BLOCK) void rope_kernel(
    const f4* __restrict__ x,
    const int* __restrict__ tok_pos,
    const f4* __restrict__ cos_t,   // (8192, 16) viewed as float4 rows
    const f4* __restrict__ sin_t,
    f4*       __restrict__ out,
    const int n_chunks)             // 32B chunks total
{
    const int tid    = blockIdx.x * BLOCK + threadIdx.x;
    const int stride = gridDim.x * BLOCK;

#pragma unroll
    for (int u = 0; u < UNROLL; ++u) {
        const int e = tid + u * stride;          // 32B-chunk index
        if (e < n_chunks) {
            const int w = e & (CH_PER_ROW - 1);  // chunk within the row
            const int s = (e >> 4) & (SEQ - 1);  // seq position (SEQ pow2)
            const int p = tok_pos[s];            // honor the gather

            // chunk covers pairs 4w..4w+3 -> float4 w of the 16-float4 table row
            const f4 c  = cos_t[p * CH_PER_ROW + w];
            const f4 sn = sin_t[p * CH_PER_ROW + w];

            const f4 a = __builtin_nontemporal_load(&x[2 * e]);
            const f4 b = __builtin_nontemporal_load(&x[2 * e + 1]);

            f4 oa, ob;
            oa.x = c.x * a.x - sn.x * a.y;
            oa.y = sn.x * a.x + c.x * a.y;
            oa.z = c.y * a.z - sn.y * a.w;
            oa.w = sn.y * a.z + c.y * a.w;
            ob.x = c.z * b.x - sn.z * b.y;
            ob.y = sn.z * b.x + c.z * b.y;
            ob.z = c.w * b.z - sn.w * b.w;
            ob.w = sn.w * b.z + c.w * b.w;

            __builtin_nontemporal_store(oa, &out[2 * e]);
            __builtin_nontemporal_store(ob, &out[2 * e + 1]);
        }
    }
}

extern "C" void kernel_launch(void* const* d_in, const int* in_sizes, int n_in,
                              void* d_out, int out_size, void* d_ws, size_t ws_size,
                              hipStream_t stream) {
    const f4*  x       = (const f4*)d_in[0];
    const int* tok_pos = (const int*)d_in[1];
    const f4*  cos_t   = (const f4*)d_in[2];
    const f4*  sin_t   = (const f4*)d_in[3];
    f4*        out     = (f4*)d_out;

    // out_size is the element (float) count: 4*16*4096*128 = 33,554,432.
    const int n_chunks = out_size / 8;               // 4,194,304 32B chunks
    const int grid = (n_chunks + BLOCK * UNROLL - 1) / (BLOCK * UNROLL);  // 4096

    rope_kernel<<<grid, BLOCK, 0, stream>>>(x, tok_pos, cos_t, sin_t, out, n_chunks);
}

// Round 4
// 228.525 us; speedup vs baseline: 1.0545x; 1.0545x over previous
//
#include <hip/hip_runtime.h>

// RoPE: out[..., 2k]   = cos*x[...,2k] - sin*x[...,2k+1]
//       out[..., 2k+1] = sin*x[...,2k] + cos*x[...,2k+1]
// x: (4,16,4096,128) fp32, tables: (8192,64) fp32, token_positions: (4096,) i32.
// Min HBM traffic 268 MB -> ~42.6 us at 6.3 TB/s copy ceiling.
//
// Round-3 lesson: 32B/thread chunks made every dwordx4 a stride-32B access
// across lanes (half-utilized cachelines per instruction) -> regressed.
// This round: keep round-0's perfect 16B/lane contiguity, and instead remove
// the tok_pos->table dependent-gather chain entirely:
//   prep kernel (once per launch, ~2 us): fused[s][j] = (cos[p][2j], sin[p][2j],
//     cos[p][2j+1], sin[p][2j+1]) with p = tok_pos[s]  -- 2 MiB, L2-resident.
//   main kernel: out[i] = rot(x[i], fused[i & 131071]) -- 3 VMEM/float4,
//     both loads independent, no indirection.

typedef float f4 __attribute__((ext_vector_type(4)));
typedef float f2 __attribute__((ext_vector_type(2)));

constexpr int SEQ        = 4096;
constexpr int D_K        = 128;
constexpr int F4_PER_ROW = D_K / 4;          // 32 float4 per 128-float row
constexpr int FUSED_F4   = SEQ * F4_PER_ROW; // 131072 float4 = 2 MiB
constexpr int BLOCK      = 256;

__global__ __launch_bounds__(BLOCK) void rope_prep(
    const int* __restrict__ tok_pos,
    const f2*  __restrict__ cos_t,   // (8192, 32) as float2
    const f2*  __restrict__ sin_t,
    f4*        __restrict__ fused)   // (4096, 32) float4
{
    const int i = blockIdx.x * BLOCK + threadIdx.x;   // 0..131071
    const int j = i & (F4_PER_ROW - 1);               // pair-couple within row
    const int s = i >> 5;                             // seq position
    const int p = tok_pos[s];                         // honor the gather ONCE here
    const f2 c  = cos_t[p * F4_PER_ROW + j];          // cos[p][2j], cos[p][2j+1]
    const f2 sn = sin_t[p * F4_PER_ROW + j];
    f4 t;
    t.x = c.x;  t.y = sn.x;  t.z = c.y;  t.w = sn.y;
    fused[i] = t;
}

__global__ __launch_bounds__(BLOCK) void rope_main(
    const f4* __restrict__ x,
    const f4* __restrict__ fused,
    f4*       __restrict__ out)
{
    const int i = blockIdx.x * BLOCK + threadIdx.x;   // float4 index, 16B/lane contiguous
    const f4 t = fused[i & (FUSED_F4 - 1)];           // L2-resident, no indirection
    const f4 v = __builtin_nontemporal_load(&x[i]);   // streamed, don't cache
    f4 o;
    o.x = t.x * v.x - t.y * v.y;
    o.y = t.y * v.x + t.x * v.y;
    o.z = t.z * v.z - t.w * v.w;
    o.w = t.w * v.z + t.z * v.w;
    __builtin_nontemporal_store(o, &out[i]);          // streamed, don't pollute L2
}

// Fallback: proven round-0 kernel (227.8 us end-to-end) if workspace too small.
__global__ __launch_bounds__(BLOCK) void rope_fallback(
    const f4* __restrict__ x,
    const int* __restrict__ tok_pos,
    const f2* __restrict__ cos_t,
    const f2* __restrict__ sin_t,
    f4*       __restrict__ out)
{
    const int i = blockIdx.x * BLOCK + threadIdx.x;
    const int within = i & (F4_PER_ROW - 1);
    const int row    = i >> 5;
    const int s      = row & (SEQ - 1);
    const int p      = tok_pos[s];
    const f2 c  = cos_t[p * F4_PER_ROW + within];
    const f2 sn = sin_t[p * F4_PER_ROW + within];
    const f4 v = x[i];
    f4 o;
    o.x = c.x * v.x - sn.x * v.y;
    o.y = sn.x * v.x + c.x * v.y;
    o.z = c.y * v.z - sn.y * v.w;
    o.w = sn.y * v.z + c.y * v.w;
    out[i] = o;
}

extern "C" void kernel_launch(void* const* d_in, const int* in_sizes, int n_in,
                              void* d_out, int out_size, void* d_ws, size_t ws_size,
                              hipStream_t stream) {
    const f4*  x       = (const f4*)d_in[0];
    const int* tok_pos = (const int*)d_in[1];
    const f2*  cos_t   = (const f2*)d_in[2];
    const f2*  sin_t   = (const f2*)d_in[3];
    f4*        out     = (f4*)d_out;

    const int n4 = out_size / 4;                      // out_size is in ELEMENTS
    const int grid = n4 / BLOCK;                      // 32768, exact

    if (ws_size >= (size_t)FUSED_F4 * 16) {
        f4* fused = (f4*)d_ws;
        rope_prep<<<FUSED_F4 / BLOCK, BLOCK, 0, stream>>>(tok_pos, cos_t, sin_t, fused);
        rope_main<<<grid, BLOCK, 0, stream>>>(x, fused, out);
    } else {
        rope_fallback<<<grid, BLOCK, 0, stream>>>(x, tok_pos, cos_t, sin_t, out);
    }
}